// Round 2
// baseline (919.085 us; speedup 1.0000x reference)
//
#include <hip/hip_runtime.h>
#include <cstdint>
#include <cstddef>

#define HIDDEN 3584
#define NH 28
#define NKV 4
#define HD 128
#define SEQ 2048
#define NB 2
#define REP (NH / NKV)   // 7
#define KVW (NKV * HD)   // 512

typedef unsigned short u16;
typedef unsigned int u32;
typedef __bf16 bf16x8 __attribute__((ext_vector_type(8)));
typedef float f32x4 __attribute__((ext_vector_type(4)));
typedef u16 u16x16 __attribute__((ext_vector_type(16)));

__device__ __forceinline__ u16 f2bf(float f) {
  u32 u = __builtin_bit_cast(u32, f);
  u = (u + 0x7fffu + ((u >> 16) & 1u)) >> 16;
  return (u16)u;
}
__device__ __forceinline__ float bf2f(u16 h) {
  u32 u = ((u32)h) << 16;
  return __builtin_bit_cast(float, u);
}

__device__ __forceinline__ void gload_lds16(const void* g, void* l) {
  __builtin_amdgcn_global_load_lds(
      (__attribute__((address_space(1))) void*)(const_cast<void*>(g)),
      (__attribute__((address_space(3))) void*)(l), 16, 0, 0);
}

// ---------------- fp32 -> bf16 conversion (exact grid, 8 elems/thread) ----
__global__ __launch_bounds__(256) void cvt_f32_bf16(const float* __restrict__ s,
                                                    u16* __restrict__ d) {
  size_t i = ((size_t)blockIdx.x * 256 + threadIdx.x) * 8;
  float4 a = *(const float4*)(s + i);
  float4 b = *(const float4*)(s + i + 4);
  u32 o0 = f2bf(a.x) | ((u32)f2bf(a.y) << 16);
  u32 o1 = f2bf(a.z) | ((u32)f2bf(a.w) << 16);
  u32 o2 = f2bf(b.x) | ((u32)f2bf(b.y) << 16);
  u32 o3 = f2bf(b.z) | ((u32)f2bf(b.w) << 16);
  uint4 o; o.x = o0; o.y = o1; o.z = o2; o.w = o3;
  *(uint4*)(d + i) = o;
}

// ---------------- RoPE in-place on bf16 [rows][nc], pairs (d, d+64) -------
template <int HALFC>
__global__ __launch_bounds__(256) void rope_ip(u16* __restrict__ X,
                                               const int* __restrict__ pos,
                                               int nc) {
  int i = blockIdx.x * 256 + threadIdx.x;
  int row = i / HALFC;
  int c = i - row * HALFC;
  int head = c >> 6, d = c & 63;
  u16* px = X + (size_t)row * nc + head * 128 + d;
  float p = (float)pos[row];
  float freq = exp2f(-(float)d * (19.93156856932417f / 64.0f));  // theta^(-2d/128)
  float ang = p * freq;
  float sv, cv;
  sincosf(ang, &sv, &cv);
  float x1 = bf2f(px[0]);
  float x2 = bf2f(px[64]);
  px[0]  = f2bf(x1 * cv - x2 * sv);
  px[64] = f2bf(x2 * cv + x1 * sv);
}

// ---------------- bf16 GEMM: C[M,N] = A[M,K] * B[N,K]^T  ------------------
// 128x128 tile, BK=32, 4 waves, global_load_lds(16B) with pre-swizzled
// global source -> linear LDS, XOR-swizzled ds_read_b128.
template <bool OUTBF>
__global__ __launch_bounds__(256) void gemm_bt(const u16* __restrict__ A,
                                               const u16* __restrict__ B,
                                               void* __restrict__ C,
                                               int M, int N, int K) {
  __shared__ u16 smA[128 * 32];
  __shared__ u16 smB[128 * 32];
  const int tid = threadIdx.x;
  const int lane = tid & 63, wave = tid >> 6;
  const int fr = lane & 15, fq = lane >> 4;
  const int aRow0 = blockIdx.y << 7;
  const int bRow0 = blockIdx.x << 7;

  // staging: byte o in tile -> row o/64, swizzled col ((o&63)^((row&3)<<4))
  const int o0 = wave * 1024 + lane * 16;
  const int r0 = o0 >> 6;
  const int c0 = ((o0 & 63) ^ ((r0 & 3) << 4)) >> 1;
  const int o1 = o0 + 4096;
  const int r1 = o1 >> 6;
  const int c1 = ((o1 & 63) ^ ((r1 & 3) << 4)) >> 1;

  const u16* gA0 = A + (size_t)(aRow0 + r0) * K + c0;
  const u16* gA1 = A + (size_t)(aRow0 + r1) * K + c1;
  const u16* gB0 = B + (size_t)(bRow0 + r0) * K + c0;
  const u16* gB1 = B + (size_t)(bRow0 + r1) * K + c1;
  u16* lA0 = smA + wave * 512;
  u16* lA1 = smA + 2048 + wave * 512;
  u16* lB0 = smB + wave * 512;
  u16* lB1 = smB + 2048 + wave * 512;

  const int wr = wave >> 1, wc = wave & 1;
  const f32x4 z4 = {0.f, 0.f, 0.f, 0.f};
  f32x4 acc[4][4];
#pragma unroll
  for (int i = 0; i < 4; i++)
#pragma unroll
    for (int j = 0; j < 4; j++) acc[i][j] = z4;

  int aoff[4], boff[4];
#pragma unroll
  for (int i = 0; i < 4; i++) {
    int ra = wr * 64 + i * 16 + fr;
    aoff[i] = ra * 64 + ((fq * 16) ^ ((ra & 3) << 4));
    int rb = wc * 64 + i * 16 + fr;
    boff[i] = rb * 64 + ((fq * 16) ^ ((rb & 3) << 4));
  }

  for (int k0 = 0; k0 < K; k0 += 32) {
    gload_lds16(gA0 + k0, lA0);
    gload_lds16(gA1 + k0, lA1);
    gload_lds16(gB0 + k0, lB0);
    gload_lds16(gB1 + k0, lB1);
    __syncthreads();
    bf16x8 av[4], bv[4];
#pragma unroll
    for (int i = 0; i < 4; i++) av[i] = *(const bf16x8*)((const char*)smA + aoff[i]);
#pragma unroll
    for (int i = 0; i < 4; i++) bv[i] = *(const bf16x8*)((const char*)smB + boff[i]);
#pragma unroll
    for (int mi = 0; mi < 4; mi++)
#pragma unroll
      for (int ni = 0; ni < 4; ni++)
        acc[mi][ni] = __builtin_amdgcn_mfma_f32_16x16x32_bf16(av[mi], bv[ni],
                                                              acc[mi][ni], 0, 0, 0);
    __syncthreads();
  }

#pragma unroll
  for (int mi = 0; mi < 4; mi++)
#pragma unroll
    for (int ni = 0; ni < 4; ni++)
#pragma unroll
      for (int r = 0; r < 4; r++) {
        int row = aRow0 + wr * 64 + mi * 16 + fq * 4 + r;
        int col = bRow0 + wc * 64 + ni * 16 + fr;
        if (OUTBF)
          ((u16*)C)[(size_t)row * N + col] = f2bf(acc[mi][ni][r]);
        else
          ((float*)C)[(size_t)row * N + col] = acc[mi][ni][r];
      }
}

// ---------------- flash attention (causal, GQA) ---------------------------
// block = (qt, h, b); 64 q-rows, 4 waves x 16 rows; KV tile = 64.
__global__ __launch_bounds__(256) void attn_fwd(const u16* __restrict__ Q,
                                                const u16* __restrict__ Kg,
                                                const u16* __restrict__ Vg,
                                                u16* __restrict__ Ob) {
  const int qt = blockIdx.x, h = blockIdx.y, b = blockIdx.z;
  const int hkv = h / REP;
  const int tid = threadIdx.x, lane = tid & 63, wave = tid >> 6;
  const int fr = lane & 15, fq = lane >> 4;

  __shared__ u16 Qs[64 * 128];
  __shared__ u16 Ks[64 * 128];
  __shared__ u16 Vt[128 * 64];   // transposed: [d][kv]
  __shared__ u16 Ps[4 * 16 * 64];

  const size_t qbase = (size_t)(b * SEQ + qt * 64) * HIDDEN + h * HD;
#pragma unroll
  for (int rd = 0; rd < 4; rd++) {
    int o = rd * 4096 + wave * 1024 + lane * 16;
    int r = o >> 8;
    int cb = (o & 255) ^ ((r & 7) << 4);
    gload_lds16(Q + qbase + (size_t)r * HIDDEN + (cb >> 1),
                (char*)Qs + (rd * 4096 + wave * 1024));
  }

  float mrow[4], lrow[4];
  const f32x4 z4 = {0.f, 0.f, 0.f, 0.f};
  f32x4 ov[8];
#pragma unroll
  for (int i = 0; i < 8; i++) ov[i] = z4;
#pragma unroll
  for (int r = 0; r < 4; r++) { mrow[r] = -1e30f; lrow[r] = 0.f; }

  const int vp = tid & 31;  // kv pair index (rows 2vp, 2vp+1)
  const int vc = tid >> 5;  // d chunk (16 wide)

  for (int j = 0; j <= qt; j++) {
    const size_t kbase = (size_t)(b * SEQ + j * 64) * KVW + hkv * HD;
#pragma unroll
    for (int rd = 0; rd < 4; rd++) {
      int o = rd * 4096 + wave * 1024 + lane * 16;
      int r = o >> 8;
      int cb = (o & 255) ^ ((r & 7) << 4);
      gload_lds16(Kg + kbase + (size_t)r * KVW + (cb >> 1),
                  (char*)Ks + (rd * 4096 + wave * 1024));
    }
    {  // V transpose into LDS: rows 2vp/2vp+1, 16 d-columns each (32B loads)
      const u16* v0 = Vg + kbase + (size_t)(2 * vp) * KVW + vc * 16;
      u16x16 ra = *(const u16x16*)v0;
      u16x16 rb = *(const u16x16*)(v0 + KVW);
#pragma unroll
      for (int i = 0; i < 16; i++) {
        int d = vc * 16 + i;
        u32 val = (u32)ra[i] | ((u32)rb[i] << 16);
        *(u32*)((char*)Vt + d * 128 + ((vp * 4) ^ ((d & 7) << 4))) = val;
      }
    }
    __syncthreads();

    // S = Q K^T (16 MFMA / wave)
    f32x4 sc[4];
#pragma unroll
    for (int ni = 0; ni < 4; ni++) sc[ni] = z4;
    const int qr = wave * 16 + fr;
#pragma unroll
    for (int kc = 0; kc < 4; kc++) {
      bf16x8 aq = *(const bf16x8*)((const char*)Qs + qr * 256 +
                                   ((kc * 64 + fq * 16) ^ ((qr & 7) << 4)));
#pragma unroll
      for (int ni = 0; ni < 4; ni++) {
        int kr = ni * 16 + fr;
        bf16x8 bk = *(const bf16x8*)((const char*)Ks + kr * 256 +
                                     ((kc * 64 + fq * 16) ^ ((kr & 7) << 4)));
        sc[ni] = __builtin_amdgcn_mfma_f32_16x16x32_bf16(aq, bk, sc[ni], 0, 0, 0);
      }
    }

    // scale + causal mask
#pragma unroll
    for (int ni = 0; ni < 4; ni++) {
      int colg = j * 64 + ni * 16 + fr;
#pragma unroll
      for (int r = 0; r < 4; r++) {
        int rowg = qt * 64 + wave * 16 + fq * 4 + r;
        float v = sc[ni][r] * 0.08838834764831845f;
        sc[ni][r] = (colg > rowg) ? -1e30f : v;
      }
    }

    // online softmax (row spread over 16 lanes)
#pragma unroll
    for (int r = 0; r < 4; r++) {
      float rm = fmaxf(fmaxf(sc[0][r], sc[1][r]), fmaxf(sc[2][r], sc[3][r]));
      rm = fmaxf(rm, __shfl_xor(rm, 1));
      rm = fmaxf(rm, __shfl_xor(rm, 2));
      rm = fmaxf(rm, __shfl_xor(rm, 4));
      rm = fmaxf(rm, __shfl_xor(rm, 8));
      float mnew = fmaxf(mrow[r], rm);
      float sf = __expf(mrow[r] - mnew);
      mrow[r] = mnew;
      float rs = 0.f;
#pragma unroll
      for (int ni = 0; ni < 4; ni++) {
        float p = __expf(sc[ni][r] - mnew);
        sc[ni][r] = p;
        rs += p;
      }
      rs += __shfl_xor(rs, 1);
      rs += __shfl_xor(rs, 2);
      rs += __shfl_xor(rs, 4);
      rs += __shfl_xor(rs, 8);
      lrow[r] = lrow[r] * sf + rs;
#pragma unroll
      for (int n2 = 0; n2 < 8; n2++) ov[n2][r] *= sf;
    }

    // P -> LDS (bf16, swizzled; per-wave region, no barrier needed)
#pragma unroll
    for (int ni = 0; ni < 4; ni++)
#pragma unroll
      for (int r = 0; r < 4; r++) {
        int prow = fq * 4 + r;
        int pcb = (ni * 16 + fr) * 2;
        *(u16*)((char*)Ps + wave * 2048 + prow * 128 +
                (pcb ^ ((prow & 7) << 4))) = f2bf(sc[ni][r]);
      }

    // O += P V (16 MFMA / wave)
#pragma unroll
    for (int kc = 0; kc < 2; kc++) {
      bf16x8 ap = *(const bf16x8*)((const char*)Ps + wave * 2048 + fr * 128 +
                                   ((kc * 64 + fq * 16) ^ ((fr & 7) << 4)));
#pragma unroll
      for (int n2 = 0; n2 < 8; n2++) {
        int vd = n2 * 16 + fr;
        bf16x8 bv = *(const bf16x8*)((const char*)Vt + vd * 128 +
                                     ((kc * 64 + fq * 16) ^ ((vd & 7) << 4)));
        ov[n2] = __builtin_amdgcn_mfma_f32_16x16x32_bf16(ap, bv, ov[n2], 0, 0, 0);
      }
    }
    __syncthreads();
  }

#pragma unroll
  for (int r = 0; r < 4; r++) {
    float inv = 1.0f / lrow[r];
    size_t rowg = (size_t)(b * SEQ + qt * 64 + wave * 16 + fq * 4 + r) * HIDDEN + h * HD;
#pragma unroll
    for (int n2 = 0; n2 < 8; n2++)
      Ob[rowg + n2 * 16 + fr] = f2bf(ov[n2][r] * inv);
  }
}

// ---------------- launch --------------------------------------------------
extern "C" void kernel_launch(void* const* d_in, const int* in_sizes, int n_in,
                              void* d_out, int out_size, void* d_ws, size_t ws_size,
                              hipStream_t stream) {
  const float* hidden = (const float*)d_in[0];
  // d_in[1] = attention_mask: exactly the causal mask -> applied analytically
  const int* pos = (const int*)d_in[2];
  const float* Wq = (const float*)d_in[3];
  const float* Wk = (const float*)d_in[4];
  const float* Wv = (const float*)d_in[5];
  const float* Wo = (const float*)d_in[6];
  float* out = (float*)d_out;
  char* ws = (char*)d_ws;

  // workspace layout (bytes), total ~120 MiB
  u16* wqb = (u16*)(ws + 0);          // 3584x3584 bf16
  u16* wkb = (u16*)(ws + 25690112);   // 512x3584
  u16* wvb = (u16*)(ws + 29360128);   // 512x3584
  u16* wob = (u16*)(ws + 33030144);   // 3584x3584
  u16* hb  = (u16*)(ws + 58720256);   // 4096x3584 (hidden bf16; later reused as attn out)
  u16* attnb = hb;
  u16* qraw = (u16*)(ws + 88080384);  // 4096x3584
  u16* kraw = (u16*)(ws + 117440512); // 4096x512
  u16* vraw = (u16*)(ws + 121634816); // 4096x512

  cvt_f32_bf16<<<7168, 256, 0, stream>>>(hidden, hb);
  cvt_f32_bf16<<<6272, 256, 0, stream>>>(Wq, wqb);
  cvt_f32_bf16<<<896, 256, 0, stream>>>(Wk, wkb);
  cvt_f32_bf16<<<896, 256, 0, stream>>>(Wv, wvb);
  cvt_f32_bf16<<<6272, 256, 0, stream>>>(Wo, wob);

  gemm_bt<true><<<dim3(28, 32), 256, 0, stream>>>(hb, wqb, qraw, 4096, 3584, 3584);
  gemm_bt<true><<<dim3(4, 32), 256, 0, stream>>>(hb, wkb, kraw, 4096, 512, 3584);
  gemm_bt<true><<<dim3(4, 32), 256, 0, stream>>>(hb, wvb, vraw, 4096, 512, 3584);

  rope_ip<1792><<<28672, 256, 0, stream>>>(qraw, pos, 3584);
  rope_ip<256><<<4096, 256, 0, stream>>>(kraw, pos, 512);

  attn_fwd<<<dim3(32, NH, NB), 256, 0, stream>>>(qraw, kraw, vraw, attnb);

  gemm_bt<false><<<dim3(28, 32), 256, 0, stream>>>(attnb, wob, out, 4096, 3584, 3584);
}

// Round 3
// 782.153 us; speedup vs baseline: 1.1751x; 1.1751x over previous
//
#include <hip/hip_runtime.h>
#include <cstdint>
#include <cstddef>

#define HIDDEN 3584
#define NH 28
#define NKV 4
#define HD 128
#define SEQ 2048
#define NB 2
#define REP (NH / NKV)   // 7
#define QSTR 4608        // fused qkv row stride (3584 + 512 + 512)
#define KOFF 3584
#define VOFF 4096

typedef unsigned short u16;
typedef unsigned int u32;
typedef __bf16 bf16x8 __attribute__((ext_vector_type(8)));
typedef float f32x4 __attribute__((ext_vector_type(4)));
typedef u16 u16x16 __attribute__((ext_vector_type(16)));

__device__ __forceinline__ u16 f2bf(float f) {
  u32 u = __builtin_bit_cast(u32, f);
  u = (u + 0x7fffu + ((u >> 16) & 1u)) >> 16;
  return (u16)u;
}
__device__ __forceinline__ float bf2f(u16 h) {
  u32 u = ((u32)h) << 16;
  return __builtin_bit_cast(float, u);
}

__device__ __forceinline__ void gload_lds16(const void* g, void* l) {
  __builtin_amdgcn_global_load_lds(
      (__attribute__((address_space(1))) void*)(const_cast<void*>(g)),
      (__attribute__((address_space(3))) void*)(l), 16, 0, 0);
}

// ---------------- fp32 -> bf16 conversion (exact grid, 8 elems/thread) ----
__global__ __launch_bounds__(256) void cvt_f32_bf16(const float* __restrict__ s,
                                                    u16* __restrict__ d) {
  size_t i = ((size_t)blockIdx.x * 256 + threadIdx.x) * 8;
  float4 a = *(const float4*)(s + i);
  float4 b = *(const float4*)(s + i + 4);
  u32 o0 = f2bf(a.x) | ((u32)f2bf(a.y) << 16);
  u32 o1 = f2bf(a.z) | ((u32)f2bf(a.w) << 16);
  u32 o2 = f2bf(b.x) | ((u32)f2bf(b.y) << 16);
  u32 o3 = f2bf(b.z) | ((u32)f2bf(b.w) << 16);
  uint4 o; o.x = o0; o.y = o1; o.z = o2; o.w = o3;
  *(uint4*)(d + i) = o;
}

// ---------------- RoPE in-place on bf16 [rows][nc], pairs (d, d+64) -------
// Applied to first HALFC*2 columns of each row (Q and K heads, identical rope).
template <int HALFC>
__global__ __launch_bounds__(256) void rope_ip(u16* __restrict__ X,
                                               const int* __restrict__ pos,
                                               int nc) {
  int i = blockIdx.x * 256 + threadIdx.x;
  int row = i / HALFC;
  int c = i - row * HALFC;
  int head = c >> 6, d = c & 63;
  u16* px = X + (size_t)row * nc + head * 128 + d;
  float p = (float)pos[row];
  float freq = exp2f(-(float)d * (19.93156856932417f / 64.0f));  // theta^(-2d/128)
  float ang = p * freq;
  float sv, cv;
  sincosf(ang, &sv, &cv);
  float x1 = bf2f(px[0]);
  float x2 = bf2f(px[64]);
  px[0]  = f2bf(x1 * cv - x2 * sv);
  px[64] = f2bf(x2 * cv + x1 * sv);
}

// ---------------- bf16 GEMM: C[M,N] = A[M,K] * B[N,K]^T  ------------------
// 128x128 tile, BK=32, 4 waves, global_load_lds(16B) with pre-swizzled
// global source -> linear LDS, XOR-swizzled ds_read_b128.
template <bool OUTBF>
__global__ __launch_bounds__(256) void gemm_bt(const u16* __restrict__ A,
                                               const u16* __restrict__ B,
                                               void* __restrict__ C,
                                               int M, int N, int K) {
  __shared__ u16 smA[128 * 32];
  __shared__ u16 smB[128 * 32];
  const int tid = threadIdx.x;
  const int lane = tid & 63, wave = tid >> 6;
  const int fr = lane & 15, fq = lane >> 4;
  const int aRow0 = blockIdx.y << 7;
  const int bRow0 = blockIdx.x << 7;

  // staging: byte o in tile -> row o/64, swizzled col ((o&63)^((row&3)<<4))
  const int o0 = wave * 1024 + lane * 16;
  const int r0 = o0 >> 6;
  const int c0 = ((o0 & 63) ^ ((r0 & 3) << 4)) >> 1;
  const int o1 = o0 + 4096;
  const int r1 = o1 >> 6;
  const int c1 = ((o1 & 63) ^ ((r1 & 3) << 4)) >> 1;

  const u16* gA0 = A + (size_t)(aRow0 + r0) * K + c0;
  const u16* gA1 = A + (size_t)(aRow0 + r1) * K + c1;
  const u16* gB0 = B + (size_t)(bRow0 + r0) * K + c0;
  const u16* gB1 = B + (size_t)(bRow0 + r1) * K + c1;
  u16* lA0 = smA + wave * 512;
  u16* lA1 = smA + 2048 + wave * 512;
  u16* lB0 = smB + wave * 512;
  u16* lB1 = smB + 2048 + wave * 512;

  const int wr = wave >> 1, wc = wave & 1;
  const f32x4 z4 = {0.f, 0.f, 0.f, 0.f};
  f32x4 acc[4][4];
#pragma unroll
  for (int i = 0; i < 4; i++)
#pragma unroll
    for (int j = 0; j < 4; j++) acc[i][j] = z4;

  int aoff[4], boff[4];
#pragma unroll
  for (int i = 0; i < 4; i++) {
    int ra = wr * 64 + i * 16 + fr;
    aoff[i] = ra * 64 + ((fq * 16) ^ ((ra & 3) << 4));
    int rb = wc * 64 + i * 16 + fr;
    boff[i] = rb * 64 + ((fq * 16) ^ ((rb & 3) << 4));
  }

  for (int k0 = 0; k0 < K; k0 += 32) {
    gload_lds16(gA0 + k0, lA0);
    gload_lds16(gA1 + k0, lA1);
    gload_lds16(gB0 + k0, lB0);
    gload_lds16(gB1 + k0, lB1);
    __syncthreads();
    bf16x8 av[4], bv[4];
#pragma unroll
    for (int i = 0; i < 4; i++) av[i] = *(const bf16x8*)((const char*)smA + aoff[i]);
#pragma unroll
    for (int i = 0; i < 4; i++) bv[i] = *(const bf16x8*)((const char*)smB + boff[i]);
#pragma unroll
    for (int mi = 0; mi < 4; mi++)
#pragma unroll
      for (int ni = 0; ni < 4; ni++)
        acc[mi][ni] = __builtin_amdgcn_mfma_f32_16x16x32_bf16(av[mi], bv[ni],
                                                              acc[mi][ni], 0, 0, 0);
    __syncthreads();
  }

#pragma unroll
  for (int mi = 0; mi < 4; mi++)
#pragma unroll
    for (int ni = 0; ni < 4; ni++)
#pragma unroll
      for (int r = 0; r < 4; r++) {
        int row = aRow0 + wr * 64 + mi * 16 + fq * 4 + r;
        int col = bRow0 + wc * 64 + ni * 16 + fr;
        if (OUTBF)
          ((u16*)C)[(size_t)row * N + col] = f2bf(acc[mi][ni][r]);
        else
          ((float*)C)[(size_t)row * N + col] = acc[mi][ni][r];
      }
}

// ---------------- flash attention (causal, GQA) ---------------------------
// block = (qx -> qt descending, h, b); 64 q-rows, 4 waves x 16 rows; KV tile 64.
// Q held in registers (wave-private rows); K,V staged in LDS. 40KB LDS ->
// 4 blocks/CU; launch_bounds(256,4) caps VGPR<=128 for 16 waves/CU.
__global__ __launch_bounds__(256, 4) void attn_fwd(const u16* __restrict__ QKV,
                                                   u16* __restrict__ Ob) {
  const int qt = 31 - blockIdx.x;  // long blocks first
  const int h = blockIdx.y, b = blockIdx.z;
  const int hkv = h / REP;
  const int tid = threadIdx.x, lane = tid & 63, wave = tid >> 6;
  const int fr = lane & 15, fq = lane >> 4;

  __shared__ u16 Ks[64 * 128];
  __shared__ u16 Vt[128 * 64];   // transposed: [d][kv]
  __shared__ u16 Ps[4 * 16 * 64];

  // Q fragments straight from global (wave-private q-rows)
  const int qr = wave * 16 + fr;
  const size_t qrow = (size_t)(b * SEQ + qt * 64 + qr) * QSTR + h * HD;
  bf16x8 qf[4];
#pragma unroll
  for (int kc = 0; kc < 4; kc++)
    qf[kc] = *(const bf16x8*)(QKV + qrow + kc * 32 + fq * 8);

  float mrow[4], lrow[4];
  const f32x4 z4 = {0.f, 0.f, 0.f, 0.f};
  f32x4 ov[8];
#pragma unroll
  for (int i = 0; i < 8; i++) ov[i] = z4;
#pragma unroll
  for (int r = 0; r < 4; r++) { mrow[r] = -1e30f; lrow[r] = 0.f; }

  const int vp = tid & 31;  // kv pair index (rows 2vp, 2vp+1)
  const int vc = tid >> 5;  // d chunk (16 wide)

  for (int j = 0; j <= qt; j++) {
    const size_t base = (size_t)(b * SEQ + j * 64) * QSTR;
    const size_t kbase = base + KOFF + hkv * HD;
    const size_t vbase = base + VOFF + hkv * HD;
#pragma unroll
    for (int rd = 0; rd < 4; rd++) {
      int o = rd * 4096 + wave * 1024 + lane * 16;
      int r = o >> 8;
      int cb = (o & 255) ^ ((r & 7) << 4);
      gload_lds16(QKV + kbase + (size_t)r * QSTR + (cb >> 1),
                  (char*)Ks + (rd * 4096 + wave * 1024));
    }
    {  // V transpose into LDS: rows 2vp/2vp+1, 16 d-columns each (32B loads)
      const u16* v0 = QKV + vbase + (size_t)(2 * vp) * QSTR + vc * 16;
      u16x16 ra = *(const u16x16*)v0;
      u16x16 rb = *(const u16x16*)(v0 + QSTR);
#pragma unroll
      for (int i = 0; i < 16; i++) {
        int d = vc * 16 + i;
        u32 val = (u32)ra[i] | ((u32)rb[i] << 16);
        *(u32*)((char*)Vt + d * 128 + ((vp * 4) ^ ((d & 7) << 4))) = val;
      }
    }
    __syncthreads();

    // S = Q K^T (16 MFMA / wave)
    f32x4 sc[4];
#pragma unroll
    for (int ni = 0; ni < 4; ni++) sc[ni] = z4;
#pragma unroll
    for (int kc = 0; kc < 4; kc++) {
#pragma unroll
      for (int ni = 0; ni < 4; ni++) {
        int kr = ni * 16 + fr;
        bf16x8 bk = *(const bf16x8*)((const char*)Ks + kr * 256 +
                                     ((kc * 64 + fq * 16) ^ ((kr & 7) << 4)));
        sc[ni] = __builtin_amdgcn_mfma_f32_16x16x32_bf16(qf[kc], bk, sc[ni], 0, 0, 0);
      }
    }

    // scale + causal mask
#pragma unroll
    for (int ni = 0; ni < 4; ni++) {
      int colg = j * 64 + ni * 16 + fr;
#pragma unroll
      for (int r = 0; r < 4; r++) {
        int rowg = qt * 64 + wave * 16 + fq * 4 + r;
        float v = sc[ni][r] * 0.08838834764831845f;
        sc[ni][r] = (colg > rowg) ? -1e30f : v;
      }
    }

    // online softmax (row spread over 16 lanes)
#pragma unroll
    for (int r = 0; r < 4; r++) {
      float rm = fmaxf(fmaxf(sc[0][r], sc[1][r]), fmaxf(sc[2][r], sc[3][r]));
      rm = fmaxf(rm, __shfl_xor(rm, 1));
      rm = fmaxf(rm, __shfl_xor(rm, 2));
      rm = fmaxf(rm, __shfl_xor(rm, 4));
      rm = fmaxf(rm, __shfl_xor(rm, 8));
      float mnew = fmaxf(mrow[r], rm);
      float sf = __expf(mrow[r] - mnew);
      mrow[r] = mnew;
      float rs = 0.f;
#pragma unroll
      for (int ni = 0; ni < 4; ni++) {
        float p = __expf(sc[ni][r] - mnew);
        sc[ni][r] = p;
        rs += p;
      }
      rs += __shfl_xor(rs, 1);
      rs += __shfl_xor(rs, 2);
      rs += __shfl_xor(rs, 4);
      rs += __shfl_xor(rs, 8);
      lrow[r] = lrow[r] * sf + rs;
#pragma unroll
      for (int n2 = 0; n2 < 8; n2++) ov[n2][r] *= sf;
    }

    // P -> LDS (bf16, swizzled; per-wave region, no barrier needed)
#pragma unroll
    for (int ni = 0; ni < 4; ni++)
#pragma unroll
      for (int r = 0; r < 4; r++) {
        int prow = fq * 4 + r;
        int pcb = (ni * 16 + fr) * 2;
        *(u16*)((char*)Ps + wave * 2048 + prow * 128 +
                (pcb ^ ((prow & 7) << 4))) = f2bf(sc[ni][r]);
      }

    // O += P V (16 MFMA / wave)
#pragma unroll
    for (int kc = 0; kc < 2; kc++) {
      bf16x8 ap = *(const bf16x8*)((const char*)Ps + wave * 2048 + fr * 128 +
                                   ((kc * 64 + fq * 16) ^ ((fr & 7) << 4)));
#pragma unroll
      for (int n2 = 0; n2 < 8; n2++) {
        int vd = n2 * 16 + fr;
        bf16x8 bv = *(const bf16x8*)((const char*)Vt + vd * 128 +
                                     ((kc * 64 + fq * 16) ^ ((vd & 7) << 4)));
        ov[n2] = __builtin_amdgcn_mfma_f32_16x16x32_bf16(ap, bv, ov[n2], 0, 0, 0);
      }
    }
    __syncthreads();
  }

#pragma unroll
  for (int r = 0; r < 4; r++) {
    float inv = 1.0f / lrow[r];
    size_t rowg = (size_t)(b * SEQ + qt * 64 + wave * 16 + fq * 4 + r) * HIDDEN + h * HD;
#pragma unroll
    for (int n2 = 0; n2 < 8; n2++)
      Ob[rowg + n2 * 16 + fr] = f2bf(ov[n2][r] * inv);
  }
}

// ---------------- launch --------------------------------------------------
extern "C" void kernel_launch(void* const* d_in, const int* in_sizes, int n_in,
                              void* d_out, int out_size, void* d_ws, size_t ws_size,
                              hipStream_t stream) {
  const float* hidden = (const float*)d_in[0];
  // d_in[1] = attention_mask: exactly the causal mask -> applied analytically
  const int* pos = (const int*)d_in[2];
  const float* Wq = (const float*)d_in[3];
  const float* Wk = (const float*)d_in[4];
  const float* Wv = (const float*)d_in[5];
  const float* Wo = (const float*)d_in[6];
  float* out = (float*)d_out;
  char* ws = (char*)d_ws;

  // workspace layout (bytes), total 120 MiB
  u16* wqkv = (u16*)(ws + 0);         // [4608][3584] bf16: Wq rows, Wk rows, Wv rows
  u16* wob  = (u16*)(ws + 33030144);  // [3584][3584]
  u16* hb   = (u16*)(ws + 58720256);  // [4096][3584] hidden bf16; reused as attn out
  u16* attnb = hb;
  u16* qkv  = (u16*)(ws + 88080384);  // [4096][4608] fused Q|K|V

  cvt_f32_bf16<<<7168, 256, 0, stream>>>(hidden, hb);
  cvt_f32_bf16<<<6272, 256, 0, stream>>>(Wq, wqkv);
  cvt_f32_bf16<<<896, 256, 0, stream>>>(Wk, wqkv + (size_t)KOFF * HIDDEN);
  cvt_f32_bf16<<<896, 256, 0, stream>>>(Wv, wqkv + (size_t)VOFF * HIDDEN);
  cvt_f32_bf16<<<6272, 256, 0, stream>>>(Wo, wob);

  // fused QKV projection: [4096, 4608] = hb[4096,3584] @ wqkv^T
  gemm_bt<true><<<dim3(36, 32), 256, 0, stream>>>(hb, wqkv, qkv, 4096, QSTR, HIDDEN);

  // RoPE over Q heads + K heads (first 4096 cols of each row)
  rope_ip<2048><<<32768, 256, 0, stream>>>(qkv, pos, QSTR);

  attn_fwd<<<dim3(32, NH, NB), 256, 0, stream>>>(qkv, attnb);

  gemm_bt<false><<<dim3(28, 32), 256, 0, stream>>>(attnb, wob, out, 4096, HIDDEN, HIDDEN);
}

// Round 4
// 627.082 us; speedup vs baseline: 1.4657x; 1.2473x over previous
//
#include <hip/hip_runtime.h>
#include <cstdint>
#include <cstddef>

#define HIDDEN 3584
#define NH 28
#define NKV 4
#define HD 128
#define SEQ 2048
#define NB 2
#define REP (NH / NKV)   // 7
#define QSTR 4608        // fused qkv row stride (3584 + 512 + 512)
#define KOFF 3584
#define VOFF 4096

typedef unsigned short u16;
typedef unsigned int u32;
typedef __bf16 bf16x8 __attribute__((ext_vector_type(8)));
typedef __bf16 bf16x2 __attribute__((ext_vector_type(2)));
typedef float f32x4 __attribute__((ext_vector_type(4)));
typedef u16 u16x16 __attribute__((ext_vector_type(16)));

__device__ __forceinline__ u16 f2bf(float f) {
  u32 u = __builtin_bit_cast(u32, f);
  u = (u + 0x7fffu + ((u >> 16) & 1u)) >> 16;
  return (u16)u;
}
__device__ __forceinline__ float bf2f(u16 h) {
  u32 u = ((u32)h) << 16;
  return __builtin_bit_cast(float, u);
}

__device__ __forceinline__ void gload_lds16(const void* g, void* l) {
  __builtin_amdgcn_global_load_lds(
      (__attribute__((address_space(1))) void*)(const_cast<void*>(g)),
      (__attribute__((address_space(3))) void*)(l), 16, 0, 0);
}

// ---------------- fp32 -> bf16 conversion (exact grid, 8 elems/thread) ----
__global__ __launch_bounds__(256) void cvt_f32_bf16(const float* __restrict__ s,
                                                    u16* __restrict__ d) {
  size_t i = ((size_t)blockIdx.x * 256 + threadIdx.x) * 8;
  float4 a = *(const float4*)(s + i);
  float4 b = *(const float4*)(s + i + 4);
  u32 o0 = f2bf(a.x) | ((u32)f2bf(a.y) << 16);
  u32 o1 = f2bf(a.z) | ((u32)f2bf(a.w) << 16);
  u32 o2 = f2bf(b.x) | ((u32)f2bf(b.y) << 16);
  u32 o3 = f2bf(b.z) | ((u32)f2bf(b.w) << 16);
  uint4 o; o.x = o0; o.y = o1; o.z = o2; o.w = o3;
  *(uint4*)(d + i) = o;
}

// ---------------- RoPE in-place on bf16 [rows][nc], pairs (d, d+64) -------
template <int HALFC>
__global__ __launch_bounds__(256) void rope_ip(u16* __restrict__ X,
                                               const int* __restrict__ pos,
                                               int nc) {
  int i = blockIdx.x * 256 + threadIdx.x;
  int row = i / HALFC;
  int c = i - row * HALFC;
  int head = c >> 6, d = c & 63;
  u16* px = X + (size_t)row * nc + head * 128 + d;
  float p = (float)pos[row];
  float freq = exp2f(-(float)d * (19.93156856932417f / 64.0f));  // theta^(-2d/128)
  float ang = p * freq;
  float sv, cv;
  sincosf(ang, &sv, &cv);
  float x1 = bf2f(px[0]);
  float x2 = bf2f(px[64]);
  px[0]  = f2bf(x1 * cv - x2 * sv);
  px[64] = f2bf(x2 * cv + x1 * sv);
}

// ---------------- bf16 GEMM: C[M,N] = A[M,K] * B[N,K]^T  ------------------
// 128x128 tile, BK=32, 4 waves, global_load_lds(16B) with pre-swizzled
// global source -> linear LDS, XOR-swizzled ds_read_b128.
template <bool OUTBF>
__global__ __launch_bounds__(256) void gemm_bt(const u16* __restrict__ A,
                                               const u16* __restrict__ B,
                                               void* __restrict__ C,
                                               int M, int N, int K) {
  __shared__ u16 smA[128 * 32];
  __shared__ u16 smB[128 * 32];
  const int tid = threadIdx.x;
  const int lane = tid & 63, wave = tid >> 6;
  const int fr = lane & 15, fq = lane >> 4;
  const int aRow0 = blockIdx.y << 7;
  const int bRow0 = blockIdx.x << 7;

  const int o0 = wave * 1024 + lane * 16;
  const int r0 = o0 >> 6;
  const int c0 = ((o0 & 63) ^ ((r0 & 3) << 4)) >> 1;
  const int o1 = o0 + 4096;
  const int r1 = o1 >> 6;
  const int c1 = ((o1 & 63) ^ ((r1 & 3) << 4)) >> 1;

  const u16* gA0 = A + (size_t)(aRow0 + r0) * K + c0;
  const u16* gA1 = A + (size_t)(aRow0 + r1) * K + c1;
  const u16* gB0 = B + (size_t)(bRow0 + r0) * K + c0;
  const u16* gB1 = B + (size_t)(bRow0 + r1) * K + c1;
  u16* lA0 = smA + wave * 512;
  u16* lA1 = smA + 2048 + wave * 512;
  u16* lB0 = smB + wave * 512;
  u16* lB1 = smB + 2048 + wave * 512;

  const int wr = wave >> 1, wc = wave & 1;
  const f32x4 z4 = {0.f, 0.f, 0.f, 0.f};
  f32x4 acc[4][4];
#pragma unroll
  for (int i = 0; i < 4; i++)
#pragma unroll
    for (int j = 0; j < 4; j++) acc[i][j] = z4;

  int aoff[4], boff[4];
#pragma unroll
  for (int i = 0; i < 4; i++) {
    int ra = wr * 64 + i * 16 + fr;
    aoff[i] = ra * 64 + ((fq * 16) ^ ((ra & 3) << 4));
    int rb = wc * 64 + i * 16 + fr;
    boff[i] = rb * 64 + ((fq * 16) ^ ((rb & 3) << 4));
  }

  for (int k0 = 0; k0 < K; k0 += 32) {
    gload_lds16(gA0 + k0, lA0);
    gload_lds16(gA1 + k0, lA1);
    gload_lds16(gB0 + k0, lB0);
    gload_lds16(gB1 + k0, lB1);
    __syncthreads();
    bf16x8 av[4], bv[4];
#pragma unroll
    for (int i = 0; i < 4; i++) av[i] = *(const bf16x8*)((const char*)smA + aoff[i]);
#pragma unroll
    for (int i = 0; i < 4; i++) bv[i] = *(const bf16x8*)((const char*)smB + boff[i]);
#pragma unroll
    for (int mi = 0; mi < 4; mi++)
#pragma unroll
      for (int ni = 0; ni < 4; ni++)
        acc[mi][ni] = __builtin_amdgcn_mfma_f32_16x16x32_bf16(av[mi], bv[ni],
                                                              acc[mi][ni], 0, 0, 0);
    __syncthreads();
  }

#pragma unroll
  for (int mi = 0; mi < 4; mi++)
#pragma unroll
    for (int ni = 0; ni < 4; ni++)
#pragma unroll
      for (int r = 0; r < 4; r++) {
        int row = aRow0 + wr * 64 + mi * 16 + fq * 4 + r;
        int col = bRow0 + wc * 64 + ni * 16 + fr;
        if (OUTBF)
          ((u16*)C)[(size_t)row * N + col] = f2bf(acc[mi][ni][r]);
        else
          ((float*)C)[(size_t)row * N + col] = acc[mi][ni][r];
      }
}

// ---------------- flash attention (causal, GQA) ---------------------------
// Swapped-operand QK^T: S = mfma(K_frag, Q_frag) -> lane holds 16 P-values of
// ONE q-row (q = lane&15, k = ni*16 + fq*4 + r). Row-max = in-reg tree + 2
// shfl_xor; row-sum deferred to per-lane partials (0 shfl/iter); defer-max
// (THR=8) skips O-rescale on the common path.
__global__ __launch_bounds__(256, 4) void attn_fwd(const u16* __restrict__ QKV,
                                                   u16* __restrict__ Ob) {
  const int qt = 31 - blockIdx.x;  // long blocks first
  const int h = blockIdx.y, b = blockIdx.z;
  const int hkv = h / REP;
  const int tid = threadIdx.x, lane = tid & 63, wave = tid >> 6;
  const int fr = lane & 15, fq = lane >> 4;

  __shared__ u16 Ks[64 * 128];
  __shared__ u16 Vt[128 * 64];   // transposed: [d][kv]
  __shared__ u16 Ps[4 * 16 * 64];

  // Q fragments straight from global (wave-private q-rows)
  const int qr = wave * 16 + fr;
  const size_t qrow = (size_t)(b * SEQ + qt * 64 + qr) * QSTR + h * HD;
  bf16x8 qf[4];
#pragma unroll
  for (int kc = 0; kc < 4; kc++)
    qf[kc] = *(const bf16x8*)(QKV + qrow + kc * 32 + fq * 8);

  // softmax state: per-lane, q-row = fr (same across fq groups)
  float mr = -1e30f;   // running row max (shared by the 4 fq lanes of row fr)
  float lp = 0.f;      // per-lane PARTIAL row sum (this lane's k-slice)
  const f32x4 z4 = {0.f, 0.f, 0.f, 0.f};
  f32x4 ov[8];
#pragma unroll
  for (int i = 0; i < 8; i++) ov[i] = z4;

  const int vp = tid & 31;  // kv pair index (rows 2vp, 2vp+1)
  const int vc = tid >> 5;  // d chunk (16 wide)

  for (int j = 0; j <= qt; j++) {
    const size_t base = (size_t)(b * SEQ + j * 64) * QSTR;
    const size_t kbase = base + KOFF + hkv * HD;
    const size_t vbase = base + VOFF + hkv * HD;
#pragma unroll
    for (int rd = 0; rd < 4; rd++) {
      int o = rd * 4096 + wave * 1024 + lane * 16;
      int r = o >> 8;
      int cb = (o & 255) ^ ((r & 7) << 4);
      gload_lds16(QKV + kbase + (size_t)r * QSTR + (cb >> 1),
                  (char*)Ks + (rd * 4096 + wave * 1024));
    }
    {  // V transpose into LDS: rows 2vp/2vp+1, 16 d-columns each (32B loads)
      const u16* v0 = QKV + vbase + (size_t)(2 * vp) * QSTR + vc * 16;
      u16x16 ra = *(const u16x16*)v0;
      u16x16 rb = *(const u16x16*)(v0 + QSTR);
#pragma unroll
      for (int i = 0; i < 16; i++) {
        int d = vc * 16 + i;
        u32 val = (u32)ra[i] | ((u32)rb[i] << 16);
        *(u32*)((char*)Vt + d * 128 + ((vp * 4) ^ ((d & 7) << 4))) = val;
      }
    }
    __syncthreads();

    // S = K Q^T (swapped): sc[ni][r] = S[k = j*64+ni*16+fq*4+r][q = wave*16+fr]
    f32x4 sc[4];
#pragma unroll
    for (int ni = 0; ni < 4; ni++) sc[ni] = z4;
#pragma unroll
    for (int kc = 0; kc < 4; kc++) {
#pragma unroll
      for (int ni = 0; ni < 4; ni++) {
        int kr = ni * 16 + fr;
        bf16x8 bk = *(const bf16x8*)((const char*)Ks + kr * 256 +
                                     ((kc * 64 + fq * 16) ^ ((kr & 7) << 4)));
        sc[ni] = __builtin_amdgcn_mfma_f32_16x16x32_bf16(bk, qf[kc], sc[ni], 0, 0, 0);
      }
    }

    // scale + causal mask (q = row fr, k in regs)
    const int rowg = qt * 64 + wave * 16 + fr;
#pragma unroll
    for (int ni = 0; ni < 4; ni++) {
#pragma unroll
      for (int r = 0; r < 4; r++) {
        int colg = j * 64 + ni * 16 + fq * 4 + r;
        float v = sc[ni][r] * 0.08838834764831845f;
        sc[ni][r] = (colg > rowg) ? -1e30f : v;
      }
    }

    // tile max: in-register tree + 2 cross-lane steps
    float pmax;
    {
      f32x4 m4 = sc[0];
#pragma unroll
      for (int ni = 1; ni < 4; ni++)
#pragma unroll
        for (int r = 0; r < 4; r++) m4[r] = fmaxf(m4[r], sc[ni][r]);
      pmax = fmaxf(fmaxf(m4[0], m4[1]), fmaxf(m4[2], m4[3]));
      pmax = fmaxf(pmax, __shfl_xor(pmax, 16));
      pmax = fmaxf(pmax, __shfl_xor(pmax, 32));
    }

    // defer-max: rescale only when the tile max beats running max by > 8
    if (__any(pmax > mr + 8.f)) {
      float mnew = fmaxf(mr, pmax);
      float sf = __expf(mr - mnew);
      mr = mnew;
      lp *= sf;
#pragma unroll
      for (int r = 0; r < 4; r++) {
        float sr = __shfl(sf, fq * 4 + r);  // sf of ov-row q = fq*4+r
#pragma unroll
        for (int n2 = 0; n2 < 8; n2++) ov[n2][r] *= sr;
      }
    }

    // exp, partial-sum accumulate, pack to bf16, P -> LDS (8 u32 stores)
    {
      char* pb = (char*)Ps + wave * 2048 + fr * 128;
      const int swz = (fr & 7) << 4;
      float lad = 0.f;
#pragma unroll
      for (int ni = 0; ni < 4; ni++) {
        float p0 = __expf(sc[ni][0] - mr);
        float p1 = __expf(sc[ni][1] - mr);
        float p2 = __expf(sc[ni][2] - mr);
        float p3 = __expf(sc[ni][3] - mr);
        lad += (p0 + p1) + (p2 + p3);
        bf16x2 w0 = {(__bf16)p0, (__bf16)p1};
        bf16x2 w1 = {(__bf16)p2, (__bf16)p3};
        int kb = ni * 32 + fq * 8;
        *(u32*)(pb + (kb ^ swz)) = __builtin_bit_cast(u32, w0);
        *(u32*)(pb + ((kb + 4) ^ swz)) = __builtin_bit_cast(u32, w1);
      }
      lp += lad;
    }

    // O += P V (16 MFMA / wave); ov rows q = fq*4+r, cols d = n2*16+fr
#pragma unroll
    for (int kc = 0; kc < 2; kc++) {
      bf16x8 ap = *(const bf16x8*)((const char*)Ps + wave * 2048 + fr * 128 +
                                   ((kc * 64 + fq * 16) ^ ((fr & 7) << 4)));
#pragma unroll
      for (int n2 = 0; n2 < 8; n2++) {
        int vd = n2 * 16 + fr;
        bf16x8 bv = *(const bf16x8*)((const char*)Vt + vd * 128 +
                                     ((kc * 64 + fq * 16) ^ ((vd & 7) << 4)));
        ov[n2] = __builtin_amdgcn_mfma_f32_16x16x32_bf16(ap, bv, ov[n2], 0, 0, 0);
      }
    }
    __syncthreads();
  }

  // final row-sum reduce (once) + normalize + store
  float ls = lp;
  ls += __shfl_xor(ls, 16);
  ls += __shfl_xor(ls, 32);
#pragma unroll
  for (int r = 0; r < 4; r++) {
    float lr = __shfl(ls, fq * 4 + r);  // row sum of ov-row q = fq*4+r
    float inv = 1.0f / lr;
    size_t rowg = (size_t)(b * SEQ + qt * 64 + wave * 16 + fq * 4 + r) * HIDDEN + h * HD;
#pragma unroll
    for (int n2 = 0; n2 < 8; n2++)
      Ob[rowg + n2 * 16 + fr] = f2bf(ov[n2][r] * inv);
  }
}

// ---------------- launch --------------------------------------------------
extern "C" void kernel_launch(void* const* d_in, const int* in_sizes, int n_in,
                              void* d_out, int out_size, void* d_ws, size_t ws_size,
                              hipStream_t stream) {
  const float* hidden = (const float*)d_in[0];
  // d_in[1] = attention_mask: exactly the causal mask -> applied analytically
  const int* pos = (const int*)d_in[2];
  const float* Wq = (const float*)d_in[3];
  const float* Wk = (const float*)d_in[4];
  const float* Wv = (const float*)d_in[5];
  const float* Wo = (const float*)d_in[6];
  float* out = (float*)d_out;
  char* ws = (char*)d_ws;

  // workspace layout (bytes), total 120 MiB
  u16* wqkv = (u16*)(ws + 0);         // [4608][3584] bf16: Wq rows, Wk rows, Wv rows
  u16* wob  = (u16*)(ws + 33030144);  // [3584][3584]
  u16* hb   = (u16*)(ws + 58720256);  // [4096][3584] hidden bf16; reused as attn out
  u16* attnb = hb;
  u16* qkv  = (u16*)(ws + 88080384);  // [4096][4608] fused Q|K|V

  cvt_f32_bf16<<<7168, 256, 0, stream>>>(hidden, hb);
  cvt_f32_bf16<<<6272, 256, 0, stream>>>(Wq, wqkv);
  cvt_f32_bf16<<<896, 256, 0, stream>>>(Wk, wqkv + (size_t)KOFF * HIDDEN);
  cvt_f32_bf16<<<896, 256, 0, stream>>>(Wv, wqkv + (size_t)VOFF * HIDDEN);
  cvt_f32_bf16<<<6272, 256, 0, stream>>>(Wo, wob);

  // fused QKV projection: [4096, 4608] = hb[4096,3584] @ wqkv^T
  gemm_bt<true><<<dim3(36, 32), 256, 0, stream>>>(hb, wqkv, qkv, 4096, QSTR, HIDDEN);

  // RoPE over Q heads + K heads (first 4096 cols of each row)
  rope_ip<2048><<<32768, 256, 0, stream>>>(qkv, pos, QSTR);

  attn_fwd<<<dim3(32, NH, NB), 256, 0, stream>>>(qkv, attnb);

  gemm_bt<false><<<dim3(28, 32), 256, 0, stream>>>(attnb, wob, out, 4096, HIDDEN, HIDDEN);
}